// Round 1
// baseline (235.440 us; speedup 1.0000x reference)
//
#include <hip/hip_runtime.h>
#include <hip/hip_bf16.h>
#include <stdint.h>

#define NSEQ 4096
#define DDIM 512
#define NB   8

#define BM 128
#define BN 128
#define BK 64

typedef float f32x4 __attribute__((ext_vector_type(4)));
typedef __bf16 bf16x8 __attribute__((ext_vector_type(8)));

typedef const void __attribute__((address_space(1))) gvoid_t;
typedef void __attribute__((address_space(3))) svoid_t;

__device__ __forceinline__ unsigned short f2bf(float f) {
    union { float f; unsigned int u; } v;
    v.f = f;
    unsigned int u = v.u;
    u += 0x7FFFu + ((u >> 16) & 1u);   // RNE
    return (unsigned short)(u >> 16);
}

// ---------------------------------------------------------------------------
// Kernel 1: materialize Toeplitz matrix T[i][j] = exp(clamp(w(i-j))) as bf16.
// w(d>0)=pos[d-1], w(0)=zero[0], w(d<0)=neg[NSEQ-1+d]
// ---------------------------------------------------------------------------
__global__ void build_T(const float* __restrict__ pos,
                        const float* __restrict__ zero,
                        const float* __restrict__ neg,
                        unsigned short* __restrict__ T) {
    int tid = blockIdx.x * blockDim.x + threadIdx.x;   // NSEQ*NSEQ/8 threads
    int i  = tid >> 9;          // 512 octets per row
    int j0 = (tid & 511) << 3;
    float z = zero[0];
    unsigned short r[8];
#pragma unroll
    for (int e = 0; e < 8; ++e) {
        int j = j0 + e;
        int d = i - j;
        float v;
        if (d > 0)       v = pos[d - 1];
        else if (d == 0) v = z;
        else             v = neg[NSEQ - 1 + d];
        v = fminf(fmaxf(v, -60.0f), 30.0f);
        r[e] = f2bf(__expf(v));
    }
    uint4 o;
    o.x = (unsigned int)r[0] | ((unsigned int)r[1] << 16);
    o.y = (unsigned int)r[2] | ((unsigned int)r[3] << 16);
    o.z = (unsigned int)r[4] | ((unsigned int)r[5] << 16);
    o.w = (unsigned int)r[6] | ((unsigned int)r[7] << 16);
    *(uint4*)(T + (size_t)i * NSEQ + j0) = o;
}

// ---------------------------------------------------------------------------
// Kernel 2: xT[b][d][j] = bf16(x[b][j][d])  (transpose + convert, 64x64 tiles)
// ---------------------------------------------------------------------------
__global__ void transpose_x(const float* __restrict__ x,
                            unsigned short* __restrict__ xT) {
    __shared__ unsigned short tile[64][66];   // stride 66 shorts: conflict-free-ish
    int b  = blockIdx.z;
    int j0 = blockIdx.x * 64;
    int d0 = blockIdx.y * 64;
    const float* xb = x + (size_t)b * NSEQ * DDIM;
#pragma unroll
    for (int e = 0; e < 16; ++e) {
        int idx = e * 256 + threadIdx.x;
        int r = idx >> 6;        // j offset
        int c = idx & 63;        // d offset (coalesced)
        tile[r][c] = f2bf(xb[(size_t)(j0 + r) * DDIM + d0 + c]);
    }
    __syncthreads();
    unsigned short* xtb = xT + (size_t)b * DDIM * NSEQ;
#pragma unroll
    for (int e = 0; e < 16; ++e) {
        int idx = e * 256 + threadIdx.x;
        int r = idx >> 6;        // d offset
        int c = idx & 63;        // j offset (coalesced)
        xtb[(size_t)(d0 + r) * NSEQ + j0 + c] = tile[c][r];
    }
}

// ---------------------------------------------------------------------------
// Kernel 3: out[b] = T @ x[b].  A = T (row-major, K-contig), B = xT (col-major
// of x, i.e. K-contig per output column).  128x128x64 tiles, 4 waves (2x2),
// 16x16x32 bf16 MFMA, acc[4][4], global_load_lds staging, 2-barrier loop.
// ---------------------------------------------------------------------------
__global__ __launch_bounds__(256) void gemm_toep(
        const unsigned short* __restrict__ T,    // [NSEQ][NSEQ] bf16
        const unsigned short* __restrict__ xT,   // [NB][DDIM][NSEQ] bf16
        float* __restrict__ out) {               // [NB][NSEQ][DDIM] f32
    __shared__ __attribute__((aligned(16))) unsigned short As[BM * BK]; // [128][64]
    __shared__ __attribute__((aligned(16))) unsigned short Bs[BN * BK]; // [128][64]

    const int tid  = threadIdx.x;
    const int lane = tid & 63;
    const int wid  = tid >> 6;
    const int i0   = blockIdx.x * BM;
    const int n0   = blockIdx.y * BN;
    const int b    = blockIdx.z;

    const unsigned short* Ag = T + (size_t)i0 * NSEQ;
    const unsigned short* Bg = xT + ((size_t)b * DDIM + n0) * NSEQ;

    f32x4 acc[4][4];
#pragma unroll
    for (int m = 0; m < 4; ++m)
#pragma unroll
        for (int nn = 0; nn < 4; ++nn)
            acc[m][nn] = (f32x4){0.f, 0.f, 0.f, 0.f};

    const int wm   = wid >> 1;        // wave row (0..1) -> 64 rows
    const int wn   = wid & 1;         // wave col (0..1) -> 64 cols
    const int lrow = lane & 15;
    const int lko  = (lane >> 4) * 8;
    const int srow = (lane >> 3);     // staging: row within 8-row segment
    const int skc  = (lane & 7) * 8;  // staging: k element offset

    for (int k0 = 0; k0 < NSEQ; k0 += BK) {
        // ---- stage A and B tiles via async global->LDS (16 B/lane) ----
#pragma unroll
        for (int c = 0; c < 4; ++c) {
            int seg = c * 4 + wid;              // 16 segments of 8 rows
            int row = seg * 8 + srow;
            __builtin_amdgcn_global_load_lds(
                (gvoid_t*)(const void*)(Ag + (size_t)row * NSEQ + k0 + skc),
                (svoid_t*)(void*)(As + seg * 512), 16, 0, 0);
            __builtin_amdgcn_global_load_lds(
                (gvoid_t*)(const void*)(Bg + (size_t)row * NSEQ + k0 + skc),
                (svoid_t*)(void*)(Bs + seg * 512), 16, 0, 0);
        }
        __syncthreads();

        // ---- MFMA over the K-tile ----
#pragma unroll
        for (int kk = 0; kk < 2; ++kk) {
            bf16x8 af[4], bfr[4];
#pragma unroll
            for (int m = 0; m < 4; ++m)
                af[m] = *(const bf16x8*)&As[(wm * 64 + m * 16 + lrow) * BK + kk * 32 + lko];
#pragma unroll
            for (int nn = 0; nn < 4; ++nn)
                bfr[nn] = *(const bf16x8*)&Bs[(wn * 64 + nn * 16 + lrow) * BK + kk * 32 + lko];
#pragma unroll
            for (int m = 0; m < 4; ++m)
#pragma unroll
                for (int nn = 0; nn < 4; ++nn)
                    acc[m][nn] = __builtin_amdgcn_mfma_f32_16x16x32_bf16(
                        af[m], bfr[nn], acc[m][nn], 0, 0, 0);
        }
        __syncthreads();
    }

    // ---- epilogue: C/D layout col=lane&15, row=(lane>>4)*4+reg ----
    float* outb = out + ((size_t)b * NSEQ + i0) * DDIM + n0;
#pragma unroll
    for (int m = 0; m < 4; ++m) {
        int gr0 = wm * 64 + m * 16 + (lane >> 4) * 4;
#pragma unroll
        for (int nn = 0; nn < 4; ++nn) {
            int gc = wn * 64 + nn * 16 + (lane & 15);
#pragma unroll
            for (int r = 0; r < 4; ++r)
                outb[(size_t)(gr0 + r) * DDIM + gc] = acc[m][nn][r];
        }
    }
}

// ---------------------------------------------------------------------------
extern "C" void kernel_launch(void* const* d_in, const int* in_sizes, int n_in,
                              void* d_out, int out_size, void* d_ws, size_t ws_size,
                              hipStream_t stream) {
    const float* x    = (const float*)d_in[0];
    const float* pos  = (const float*)d_in[1];
    const float* zero = (const float*)d_in[2];
    const float* neg  = (const float*)d_in[3];
    float* out = (float*)d_out;

    unsigned short* Tm = (unsigned short*)d_ws;                    // 32 MiB
    unsigned short* xT = Tm + (size_t)NSEQ * NSEQ;                 // 32 MiB

    build_T<<<dim3(NSEQ * NSEQ / 8 / 256), 256, 0, stream>>>(pos, zero, neg, Tm);
    transpose_x<<<dim3(NSEQ / 64, DDIM / 64, NB), 256, 0, stream>>>(x, xT);
    gemm_toep<<<dim3(NSEQ / BM, DDIM / BN, NB), 256, 0, stream>>>(Tm, xT, out);
}

// Round 2
// 171.885 us; speedup vs baseline: 1.3698x; 1.3698x over previous
//
#include <hip/hip_runtime.h>
#include <hip/hip_bf16.h>
#include <stdint.h>

#define NSEQ 4096
#define DDIM 512
#define NB   8

#define BMN 256
#define BK  64
#define NT  (NSEQ / BK)   // 64 K-tiles

typedef float f32x4 __attribute__((ext_vector_type(4)));
typedef __bf16 bf16x8 __attribute__((ext_vector_type(8)));

typedef const void __attribute__((address_space(1))) gvoid_t;
typedef void __attribute__((address_space(3))) svoid_t;

// barrier with compiler memory-ordering pin (raw s_barrier has no memory
// semantics for LLVM; the empty asm keeps LDS ops / gload_lds from crossing)
#define SBAR() do { __builtin_amdgcn_s_barrier(); asm volatile("" ::: "memory"); } while (0)

__device__ __forceinline__ unsigned short f2bf(float f) {
    union { float f; unsigned int u; } v;
    v.f = f;
    unsigned int u = v.u;
    u += 0x7FFFu + ((u >> 16) & 1u);   // RNE
    return (unsigned short)(u >> 16);
}

// ---------------------------------------------------------------------------
// Kernel 1: T[i][j] = bf16(exp(clamp(w(i-j)))), w(d>0)=pos[d-1], w(0)=zero,
// w(d<0)=neg[NSEQ-1+d]
// ---------------------------------------------------------------------------
__global__ void build_T(const float* __restrict__ pos,
                        const float* __restrict__ zero,
                        const float* __restrict__ neg,
                        unsigned short* __restrict__ T) {
    int tid = blockIdx.x * blockDim.x + threadIdx.x;
    int i  = tid >> 9;
    int j0 = (tid & 511) << 3;
    float z = zero[0];
    unsigned short r[8];
#pragma unroll
    for (int e = 0; e < 8; ++e) {
        int j = j0 + e;
        int d = i - j;
        float v;
        if (d > 0)       v = pos[d - 1];
        else if (d == 0) v = z;
        else             v = neg[NSEQ - 1 + d];
        v = fminf(fmaxf(v, -60.0f), 30.0f);
        r[e] = f2bf(__expf(v));
    }
    uint4 o;
    o.x = (unsigned int)r[0] | ((unsigned int)r[1] << 16);
    o.y = (unsigned int)r[2] | ((unsigned int)r[3] << 16);
    o.z = (unsigned int)r[4] | ((unsigned int)r[5] << 16);
    o.w = (unsigned int)r[6] | ((unsigned int)r[7] << 16);
    *(uint4*)(T + (size_t)i * NSEQ + j0) = o;
}

// ---------------------------------------------------------------------------
// Kernel 2: xT[b][d][j] = bf16(x[b][j][d])
// ---------------------------------------------------------------------------
__global__ void transpose_x(const float* __restrict__ x,
                            unsigned short* __restrict__ xT) {
    __shared__ unsigned short tile[64][66];
    int b  = blockIdx.z;
    int j0 = blockIdx.x * 64;
    int d0 = blockIdx.y * 64;
    const float* xb = x + (size_t)b * NSEQ * DDIM;
#pragma unroll
    for (int e = 0; e < 16; ++e) {
        int idx = e * 256 + threadIdx.x;
        int r = idx >> 6, c = idx & 63;
        tile[r][c] = f2bf(xb[(size_t)(j0 + r) * DDIM + d0 + c]);
    }
    __syncthreads();
    unsigned short* xtb = xT + (size_t)b * DDIM * NSEQ;
#pragma unroll
    for (int e = 0; e < 16; ++e) {
        int idx = e * 256 + threadIdx.x;
        int r = idx >> 6, c = idx & 63;
        xtb[(size_t)(d0 + r) * NSEQ + j0 + c] = tile[c][r];
    }
}

// ---------------------------------------------------------------------------
// Kernel 3: out[b] = T @ x[b].  256x256x64 tiles, 8 waves (2M x 4N), 512 thr.
// Deep pipeline: 2-tile prefetch, counted vmcnt(8), 4 phases/K-tile with
// 2 barriers each, setprio around MFMA, XOR-swizzled LDS (chunk ^= row&7),
// bijective XCD blockIdx swizzle.
// ---------------------------------------------------------------------------
__global__ __launch_bounds__(512, 2) void gemm_toep8(
        const unsigned short* __restrict__ T,    // [NSEQ][NSEQ] bf16
        const unsigned short* __restrict__ xT,   // [NB][DDIM][NSEQ] bf16
        float* __restrict__ out) {               // [NB][NSEQ][DDIM] f32
    // [buf][op A=0/B=1][256 rows][64 k]  -> 128 KiB
    __shared__ __attribute__((aligned(16))) unsigned short lds[2][2][BMN * BK];

    const int tid  = threadIdx.x;
    const int lane = tid & 63;
    const int wid  = tid >> 6;      // 0..7
    const int wm   = wid >> 2;      // 0..1 -> 128-row half
    const int wn   = wid & 3;       // 0..3 -> 64-col quarter
    const int lrow = lane & 15;
    const int lhi  = lane >> 4;     // 0..3

    // ---- XCD-aware bijective block swizzle (256 blocks, 8 XCDs) ----
    int lin = blockIdx.x;
    int swz = (lin & 7) * 32 + (lin >> 3);
    int it  = swz >> 4;             // i-tile 0..15
    int tn  = (swz & 15) & 1;       // n-tile 0..1
    int b   = (swz & 15) >> 1;      // batch 0..7
    const int i0 = it * BMN;
    const int n0 = tn * BMN;

    const unsigned short* Ag = T + (size_t)i0 * NSEQ;
    const unsigned short* Bg = xT + ((size_t)b * DDIM + n0) * NSEQ;

    // ---- staging geometry: per instr = 8 rows x 128B; wave w octets q*8+w ----
    const int srow = lane >> 3;                 // row within octet
    const int schk = (lane & 7) ^ srow;         // pre-swizzled source chunk
    uint32_t offs[4];
#pragma unroll
    for (int q = 0; q < 4; ++q)
        offs[q] = (uint32_t)((q * 8 + wid) * 8 + srow) * NSEQ + schk * 8;

    // ---- read-side swizzled chunk offsets (in ushorts) ----
    const int ca0 = ((0 + lhi) ^ (lrow & 7)) * 8;
    const int ca1 = ((4 + lhi) ^ (lrow & 7)) * 8;

    auto stage_tile = [&](int buf, int k0) {
        unsigned short* As = &lds[buf][0][0];
        unsigned short* Bs = &lds[buf][1][0];
#pragma unroll
        for (int q = 0; q < 4; ++q) {
            int oct = q * 8 + wid;
            __builtin_amdgcn_global_load_lds(
                (gvoid_t*)(const void*)(Ag + offs[q] + k0),
                (svoid_t*)(void*)(As + oct * 512), 16, 0, 0);
            __builtin_amdgcn_global_load_lds(
                (gvoid_t*)(const void*)(Bg + offs[q] + k0),
                (svoid_t*)(void*)(Bs + oct * 512), 16, 0, 0);
        }
    };

    f32x4 acc[8][4];
#pragma unroll
    for (int m = 0; m < 8; ++m)
#pragma unroll
        for (int n = 0; n < 4; ++n)
            acc[m][n] = (f32x4){0.f, 0.f, 0.f, 0.f};

    stage_tile(0, 0);
    stage_tile(1, BK);

    for (int kt = 0; kt < NT; ++kt) {
        const int cur = kt & 1;
        if (kt == NT - 1) { asm volatile("s_waitcnt vmcnt(0)" ::: "memory"); }
        else              { asm volatile("s_waitcnt vmcnt(8)" ::: "memory"); }
        SBAR();   // all waves' tile-kt octets landed before anyone reads

        const unsigned short* As = &lds[cur][0][0];
        const unsigned short* Bs = &lds[cur][1][0];
        bf16x8 bfr[4][2];

#pragma unroll
        for (int p = 0; p < 4; ++p) {
            if (p == 0) {
#pragma unroll
                for (int n = 0; n < 4; ++n) {
                    int rbase = (wn * 64 + n * 16 + lrow) * BK;
                    bfr[n][0] = *(const bf16x8*)&Bs[rbase + ca0];
                    bfr[n][1] = *(const bf16x8*)&Bs[rbase + ca1];
                }
            }
            bf16x8 af[2][2];
#pragma unroll
            for (int m2 = 0; m2 < 2; ++m2) {
                int rbase = (wm * 128 + (2 * p + m2) * 16 + lrow) * BK;
                af[m2][0] = *(const bf16x8*)&As[rbase + ca0];
                af[m2][1] = *(const bf16x8*)&As[rbase + ca1];
            }
            SBAR();
            asm volatile("s_waitcnt lgkmcnt(0)" ::: "memory");
            __builtin_amdgcn_sched_barrier(0);
            __builtin_amdgcn_s_setprio(1);
#pragma unroll
            for (int kk = 0; kk < 2; ++kk)
#pragma unroll
                for (int m2 = 0; m2 < 2; ++m2)
#pragma unroll
                    for (int n = 0; n < 4; ++n)
                        acc[2 * p + m2][n] = __builtin_amdgcn_mfma_f32_16x16x32_bf16(
                            af[m2][kk], bfr[n][kk], acc[2 * p + m2][n], 0, 0, 0);
            __builtin_amdgcn_s_setprio(0);
            SBAR();
        }
        // buf cur fully consumed by ALL waves (lgkm0 + barrier) -> safe to
        // issue next-next tile's DMA into it
        if (kt + 2 < NT) stage_tile(cur, (kt + 2) * BK);
    }

    // ---- epilogue: C/D layout col=lane&15, row=(lane>>4)*4+r ----
    float* outb = out + ((size_t)b * NSEQ + i0 + wm * 128) * DDIM + n0 + wn * 64;
#pragma unroll
    for (int m = 0; m < 8; ++m)
#pragma unroll
        for (int n = 0; n < 4; ++n)
#pragma unroll
            for (int r = 0; r < 4; ++r)
                outb[(size_t)(m * 16 + lhi * 4 + r) * DDIM + n * 16 + lrow] = acc[m][n][r];
}

// ---------------------------------------------------------------------------
extern "C" void kernel_launch(void* const* d_in, const int* in_sizes, int n_in,
                              void* d_out, int out_size, void* d_ws, size_t ws_size,
                              hipStream_t stream) {
    const float* x    = (const float*)d_in[0];
    const float* pos  = (const float*)d_in[1];
    const float* zero = (const float*)d_in[2];
    const float* neg  = (const float*)d_in[3];
    float* out = (float*)d_out;

    unsigned short* Tm = (unsigned short*)d_ws;                    // 32 MiB
    unsigned short* xT = Tm + (size_t)NSEQ * NSEQ;                 // 32 MiB

    build_T<<<dim3(NSEQ * NSEQ / 8 / 256), 256, 0, stream>>>(pos, zero, neg, Tm);
    transpose_x<<<dim3(NSEQ / 64, DDIM / 64, NB), 256, 0, stream>>>(x, xT);
    gemm_toep8<<<dim3(NSEQ / BMN * (DDIM / BMN) * NB), 512, 0, stream>>>(Tm, xT, out);
}

// Round 3
// 167.033 us; speedup vs baseline: 1.4095x; 1.0291x over previous
//
#include <hip/hip_runtime.h>
#include <hip/hip_bf16.h>
#include <stdint.h>

#define NSEQ 4096
#define DDIM 512
#define NB   8

#define BMN 256
#define BK  64
#define NT  (NSEQ / BK)   // 64 K-tiles

typedef float f32x4 __attribute__((ext_vector_type(4)));
typedef __bf16 bf16x8 __attribute__((ext_vector_type(8)));

typedef const void __attribute__((address_space(1))) gvoid_t;
typedef void __attribute__((address_space(3))) svoid_t;

#define SBAR() do { __builtin_amdgcn_s_barrier(); asm volatile("" ::: "memory"); } while (0)

__device__ __forceinline__ unsigned short f2bf(float f) {
    union { float f; unsigned int u; } v;
    v.f = f;
    unsigned int u = v.u;
    u += 0x7FFFu + ((u >> 16) & 1u);   // RNE
    return (unsigned short)(u >> 16);
}

// ---------------------------------------------------------------------------
// Kernel 1: T[i][j] = bf16(exp(clamp(w(i-j))))
// ---------------------------------------------------------------------------
__global__ void build_T(const float* __restrict__ pos,
                        const float* __restrict__ zero,
                        const float* __restrict__ neg,
                        unsigned short* __restrict__ T) {
    int tid = blockIdx.x * blockDim.x + threadIdx.x;
    int i  = tid >> 9;
    int j0 = (tid & 511) << 3;
    float z = zero[0];
    unsigned short r[8];
#pragma unroll
    for (int e = 0; e < 8; ++e) {
        int j = j0 + e;
        int d = i - j;
        float v;
        if (d > 0)       v = pos[d - 1];
        else if (d == 0) v = z;
        else             v = neg[NSEQ - 1 + d];
        v = fminf(fmaxf(v, -60.0f), 30.0f);
        r[e] = f2bf(__expf(v));
    }
    uint4 o;
    o.x = (unsigned int)r[0] | ((unsigned int)r[1] << 16);
    o.y = (unsigned int)r[2] | ((unsigned int)r[3] << 16);
    o.z = (unsigned int)r[4] | ((unsigned int)r[5] << 16);
    o.w = (unsigned int)r[6] | ((unsigned int)r[7] << 16);
    *(uint4*)(T + (size_t)i * NSEQ + j0) = o;
}

// ---------------------------------------------------------------------------
// Kernel 2: xT[b][d][j] = bf16(x[b][j][d])
// ---------------------------------------------------------------------------
__global__ void transpose_x(const float* __restrict__ x,
                            unsigned short* __restrict__ xT) {
    __shared__ unsigned short tile[64][66];
    int b  = blockIdx.z;
    int j0 = blockIdx.x * 64;
    int d0 = blockIdx.y * 64;
    const float* xb = x + (size_t)b * NSEQ * DDIM;
#pragma unroll
    for (int e = 0; e < 16; ++e) {
        int idx = e * 256 + threadIdx.x;
        int r = idx >> 6, c = idx & 63;
        tile[r][c] = f2bf(xb[(size_t)(j0 + r) * DDIM + d0 + c]);
    }
    __syncthreads();
    unsigned short* xtb = xT + (size_t)b * DDIM * NSEQ;
#pragma unroll
    for (int e = 0; e < 16; ++e) {
        int idx = e * 256 + threadIdx.x;
        int r = idx >> 6, c = idx & 63;
        xtb[(size_t)(d0 + r) * NSEQ + j0 + c] = tile[c][r];
    }
}

// ---------------------------------------------------------------------------
// Kernel 3: out[b] = T @ x[b].  256x256x64 tiles, 8 waves (2M x 4N), 512 thr.
// 2-deep DMA prefetch, counted vmcnt(8), TWO barriers per K-tile, software-
// pipelined A-fragment ds_reads with counted lgkmcnt(4) so LDS-read and MFMA
// pipes overlap across free-running waves. setprio around MFMA clusters.
// XOR-swizzled LDS (chunk ^= row&7, both-sides), bijective XCD block swizzle.
// ---------------------------------------------------------------------------
__global__ __launch_bounds__(512, 2) void gemm_toep8(
        const unsigned short* __restrict__ T,    // [NSEQ][NSEQ] bf16
        const unsigned short* __restrict__ xT,   // [NB][DDIM][NSEQ] bf16
        float* __restrict__ out) {               // [NB][NSEQ][DDIM] f32
    __shared__ __attribute__((aligned(16))) unsigned short lds[2][2][BMN * BK];

    const int tid  = threadIdx.x;
    const int lane = tid & 63;
    const int wid  = tid >> 6;      // 0..7
    const int wm   = wid >> 2;      // 0..1 -> 128-row half
    const int wn   = wid & 3;       // 0..3 -> 64-col quarter
    const int lrow = lane & 15;
    const int lhi  = lane >> 4;     // 0..3

    // ---- XCD-aware bijective block swizzle (256 blocks, 8 XCDs) ----
    int lin = blockIdx.x;
    int swz = (lin & 7) * 32 + (lin >> 3);
    int it  = swz >> 4;             // i-tile 0..15
    int tn  = (swz & 15) & 1;       // n-tile 0..1
    int b   = (swz & 15) >> 1;      // batch 0..7
    const int i0 = it * BMN;
    const int n0 = tn * BMN;

    const unsigned short* Ag = T + (size_t)i0 * NSEQ;
    const unsigned short* Bg = xT + ((size_t)b * DDIM + n0) * NSEQ;

    // staging: per instr = 8 rows x 128B, pre-swizzled source chunk
    const int srow = lane >> 3;
    const int schk = (lane & 7) ^ srow;
    uint32_t offs[4];
#pragma unroll
    for (int q = 0; q < 4; ++q)
        offs[q] = (uint32_t)((q * 8 + wid) * 8 + srow) * NSEQ + schk * 8;

    // read-side swizzled chunk offsets (ushort units)
    const int ca0 = ((0 + lhi) ^ (lrow & 7)) * 8;
    const int ca1 = ((4 + lhi) ^ (lrow & 7)) * 8;

    auto stage_tile = [&](int buf, int k0) {
        unsigned short* As = &lds[buf][0][0];
        unsigned short* Bs = &lds[buf][1][0];
#pragma unroll
        for (int q = 0; q < 4; ++q) {
            int oct = q * 8 + wid;
            __builtin_amdgcn_global_load_lds(
                (gvoid_t*)(const void*)(Ag + offs[q] + k0),
                (svoid_t*)(void*)(As + oct * 512), 16, 0, 0);
            __builtin_amdgcn_global_load_lds(
                (gvoid_t*)(const void*)(Bg + offs[q] + k0),
                (svoid_t*)(void*)(Bs + oct * 512), 16, 0, 0);
        }
    };

    f32x4 acc[8][4];
#pragma unroll
    for (int m = 0; m < 8; ++m)
#pragma unroll
        for (int n = 0; n < 4; ++n)
            acc[m][n] = (f32x4){0.f, 0.f, 0.f, 0.f};

    stage_tile(0, 0);
    stage_tile(1, BK);

    for (int kt = 0; kt < NT; ++kt) {
        const int cur = kt & 1;
        if (kt == NT - 1) { asm volatile("s_waitcnt vmcnt(0)" ::: "memory"); }
        else              { asm volatile("s_waitcnt vmcnt(8)" ::: "memory"); }
        SBAR();   // all waves' tile-kt octets landed

        const unsigned short* As = &lds[cur][0][0];
        const unsigned short* Bs = &lds[cur][1][0];

        // B fragments (held all tile) + A phase-0 fragments
        bf16x8 bfr[4][2];
#pragma unroll
        for (int n = 0; n < 4; ++n) {
            int rbase = (wn * 64 + n * 16 + lrow) * BK;
            bfr[n][0] = *(const bf16x8*)&Bs[rbase + ca0];
            bfr[n][1] = *(const bf16x8*)&Bs[rbase + ca1];
        }
        bf16x8 af[2][2][2];   // [pingpong][m2][chunk]
#pragma unroll
        for (int m2 = 0; m2 < 2; ++m2) {
            int rbase = (wm * 128 + m2 * 16 + lrow) * BK;
            af[0][m2][0] = *(const bf16x8*)&As[rbase + ca0];
            af[0][m2][1] = *(const bf16x8*)&As[rbase + ca1];
        }

#pragma unroll
        for (int p = 0; p < 4; ++p) {
            if (p < 3) {   // issue next phase's A-reads before waiting
#pragma unroll
                for (int m2 = 0; m2 < 2; ++m2) {
                    int rbase = (wm * 128 + (2 * (p + 1) + m2) * 16 + lrow) * BK;
                    af[(p + 1) & 1][m2][0] = *(const bf16x8*)&As[rbase + ca0];
                    af[(p + 1) & 1][m2][1] = *(const bf16x8*)&As[rbase + ca1];
                }
                asm volatile("s_waitcnt lgkmcnt(4)" ::: "memory");
            } else {
                asm volatile("s_waitcnt lgkmcnt(0)" ::: "memory");
            }
            __builtin_amdgcn_sched_barrier(0);
            __builtin_amdgcn_s_setprio(1);
#pragma unroll
            for (int kk = 0; kk < 2; ++kk)
#pragma unroll
                for (int m2 = 0; m2 < 2; ++m2)
#pragma unroll
                    for (int n = 0; n < 4; ++n)
                        acc[2 * p + m2][n] = __builtin_amdgcn_mfma_f32_16x16x32_bf16(
                            af[p & 1][m2][kk], bfr[n][kk], acc[2 * p + m2][n], 0, 0, 0);
            __builtin_amdgcn_s_setprio(0);
        }
        SBAR();   // all waves done reading buf cur -> safe to re-stage it
        if (kt + 2 < NT) stage_tile(cur, (kt + 2) * BK);
    }

    // ---- epilogue: C/D layout col=lane&15, row=(lane>>4)*4+r ----
    float* outb = out + ((size_t)b * NSEQ + i0 + wm * 128) * DDIM + n0 + wn * 64;
#pragma unroll
    for (int m = 0; m < 8; ++m)
#pragma unroll
        for (int n = 0; n < 4; ++n)
#pragma unroll
            for (int r = 0; r < 4; ++r)
                outb[(size_t)(m * 16 + lhi * 4 + r) * DDIM + n * 16 + lrow] = acc[m][n][r];
}

// ---------------------------------------------------------------------------
extern "C" void kernel_launch(void* const* d_in, const int* in_sizes, int n_in,
                              void* d_out, int out_size, void* d_ws, size_t ws_size,
                              hipStream_t stream) {
    const float* x    = (const float*)d_in[0];
    const float* pos  = (const float*)d_in[1];
    const float* zero = (const float*)d_in[2];
    const float* neg  = (const float*)d_in[3];
    float* out = (float*)d_out;

    unsigned short* Tm = (unsigned short*)d_ws;                    // 32 MiB
    unsigned short* xT = Tm + (size_t)NSEQ * NSEQ;                 // 32 MiB

    build_T<<<dim3(NSEQ * NSEQ / 8 / 256), 256, 0, stream>>>(pos, zero, neg, Tm);
    transpose_x<<<dim3(NSEQ / 64, DDIM / 64, NB), 256, 0, stream>>>(x, xT);
    gemm_toep8<<<dim3(NSEQ / BMN * (DDIM / BMN) * NB), 512, 0, stream>>>(Tm, xT, out);
}

// Round 4
// 164.127 us; speedup vs baseline: 1.4345x; 1.0177x over previous
//
#include <hip/hip_runtime.h>
#include <hip/hip_bf16.h>
#include <stdint.h>

#define NSEQ 4096
#define DDIM 512
#define NB   8

#define BMN 256
#define BK  64
#define NT  (NSEQ / BK)   // 64 K-tiles

typedef float f32x4 __attribute__((ext_vector_type(4)));
typedef __bf16 bf16x8 __attribute__((ext_vector_type(8)));

typedef const void __attribute__((address_space(1))) gvoid_t;
typedef void __attribute__((address_space(3))) svoid_t;

#define SBAR() do { __builtin_amdgcn_s_barrier(); asm volatile("" ::: "memory"); } while (0)

__device__ __forceinline__ unsigned short f2bf(float f) {
    union { float f; unsigned int u; } v;
    v.f = f;
    unsigned int u = v.u;
    u += 0x7FFFu + ((u >> 16) & 1u);   // RNE
    return (unsigned short)(u >> 16);
}

// ---------------------------------------------------------------------------
// Kernel 1: T[i][j] = bf16(exp(clamp(w(i-j))))
// ---------------------------------------------------------------------------
__global__ void build_T(const float* __restrict__ pos,
                        const float* __restrict__ zero,
                        const float* __restrict__ neg,
                        unsigned short* __restrict__ T) {
    int tid = blockIdx.x * blockDim.x + threadIdx.x;
    int i  = tid >> 9;
    int j0 = (tid & 511) << 3;
    float z = zero[0];
    unsigned short r[8];
#pragma unroll
    for (int e = 0; e < 8; ++e) {
        int j = j0 + e;
        int d = i - j;
        float v;
        if (d > 0)       v = pos[d - 1];
        else if (d == 0) v = z;
        else             v = neg[NSEQ - 1 + d];
        v = fminf(fmaxf(v, -60.0f), 30.0f);
        r[e] = f2bf(__expf(v));
    }
    uint4 o;
    o.x = (unsigned int)r[0] | ((unsigned int)r[1] << 16);
    o.y = (unsigned int)r[2] | ((unsigned int)r[3] << 16);
    o.z = (unsigned int)r[4] | ((unsigned int)r[5] << 16);
    o.w = (unsigned int)r[6] | ((unsigned int)r[7] << 16);
    *(uint4*)(T + (size_t)i * NSEQ + j0) = o;
}

// ---------------------------------------------------------------------------
// Kernel 2: xT[b][d][j] = bf16(x[b][j][d])
// ---------------------------------------------------------------------------
__global__ void transpose_x(const float* __restrict__ x,
                            unsigned short* __restrict__ xT) {
    __shared__ unsigned short tile[64][66];
    int b  = blockIdx.z;
    int j0 = blockIdx.x * 64;
    int d0 = blockIdx.y * 64;
    const float* xb = x + (size_t)b * NSEQ * DDIM;
#pragma unroll
    for (int e = 0; e < 16; ++e) {
        int idx = e * 256 + threadIdx.x;
        int r = idx >> 6, c = idx & 63;
        tile[r][c] = f2bf(xb[(size_t)(j0 + r) * DDIM + d0 + c]);
    }
    __syncthreads();
    unsigned short* xtb = xT + (size_t)b * DDIM * NSEQ;
#pragma unroll
    for (int e = 0; e < 16; ++e) {
        int idx = e * 256 + threadIdx.x;
        int r = idx >> 6, c = idx & 63;
        xtb[(size_t)(d0 + r) * NSEQ + j0 + c] = tile[c][r];
    }
}

// ---------------------------------------------------------------------------
// Kernel 3: out[b] = T @ x[b] exploiting Toeplitz A-fragment reuse.
// 256x256x64 tiles, 8 waves (2M x 4N), 512 thr.  A-frags live in a 10-slot
// register ring (rotating base, period 5, K-loop unrolled x5 -> static idx);
// only 4 fresh A-frags + 8 B-frags read from LDS per tile.  A staged rows
// {0..31,128..159} only (8 KB).  2 barriers + 1 vmcnt(0) per tile.
// ---------------------------------------------------------------------------
__global__ __launch_bounds__(512, 2) void gemm_toep_ring(
        const unsigned short* __restrict__ T,    // [NSEQ][NSEQ] bf16
        const unsigned short* __restrict__ xT,   // [NB][DDIM][NSEQ] bf16
        float* __restrict__ out) {               // [NB][NSEQ][DDIM] f32
    __shared__ __attribute__((aligned(16))) unsigned short sA[2][64 * BK];   // 8 KB each
    __shared__ __attribute__((aligned(16))) unsigned short sB[2][BMN * BK];  // 32 KB each

    const int tid  = threadIdx.x;
    const int lane = tid & 63;
    const int wid  = tid >> 6;      // 0..7
    const int wm   = wid >> 2;      // 0..1 -> 128-row half
    const int wn   = wid & 3;       // 0..3 -> 64-col quarter
    const int lrow = lane & 15;
    const int lhi  = lane >> 4;     // 0..3

    // ---- XCD-aware bijective block swizzle (256 blocks, 8 XCDs) ----
    int lin = blockIdx.x;
    int swz = (lin & 7) * 32 + (lin >> 3);
    int it  = swz >> 4;
    int tn  = (swz & 15) & 1;
    int b   = (swz & 15) >> 1;
    const int i0 = it * BMN;
    const int n0 = tn * BMN;

    const unsigned short* Ag = T + (size_t)i0 * NSEQ;
    const unsigned short* Bg = xT + ((size_t)b * DDIM + n0) * NSEQ;

    // staging geometry: 8 rows x 128B per instr, pre-swizzled source chunk
    const int srow = lane >> 3;
    const int schk = (lane & 7) ^ srow;
    // A: wave wid stages octet wid -> global rows {0..31, 128..159}
    const int agrow = (wid < 4) ? (wid * 8 + srow) : (128 + (wid - 4) * 8 + srow);
    const uint32_t offA = (uint32_t)agrow * NSEQ + schk * 8;
    uint32_t offB[4];
#pragma unroll
    for (int q = 0; q < 4; ++q)
        offB[q] = (uint32_t)((q * 8 + wid) * 8 + srow) * NSEQ + schk * 8;

    // read-side swizzled chunk offsets (ushort units): kk=0 -> ca0, kk=1 -> ca1
    const int ca0 = ((0 + lhi) ^ (lrow & 7)) * 8;
    const int ca1 = ((4 + lhi) ^ (lrow & 7)) * 8;

    auto stage_tile = [&](int buf, int k0) {
        __builtin_amdgcn_global_load_lds(
            (gvoid_t*)(const void*)(Ag + offA + k0),
            (svoid_t*)(void*)(&sA[buf][0] + wid * 512), 16, 0, 0);
#pragma unroll
        for (int q = 0; q < 4; ++q)
            __builtin_amdgcn_global_load_lds(
                (gvoid_t*)(const void*)(Bg + offB[q] + k0),
                (svoid_t*)(void*)(&sB[buf][0] + (q * 8 + wid) * 512), 16, 0, 0);
    };

    f32x4 acc[8][4];
#pragma unroll
    for (int m = 0; m < 8; ++m)
#pragma unroll
        for (int n = 0; n < 4; ++n)
            acc[m][n] = (f32x4){0.f, 0.f, 0.f, 0.f};

    // ---- A-fragment register ring: 10 slots, base rotates +6 (mod 10)/tile.
    // phys(logical r, tile t) = (r + base_t) % 10, base_t = 6t % 10.
    // logical r <-> frag(mt,kk): r = mt + 2 - 2kk.
    bf16x8 af[10];
    // ring init for tile 0 (base=0) straight from global T (one time):
#pragma unroll
    for (int r = 0; r < 10; ++r) {
        int mt = (r <= 7) ? r : r - 2;
        int kk = (r <= 7) ? 1 : 0;
        af[r] = *(const bf16x8*)(T +
            (size_t)(i0 + wm * 128 + mt * 16 + lrow) * NSEQ + kk * 32 + lhi * 8);
    }

    stage_tile(0, 0);
    stage_tile(1, BK);
    asm volatile("s_waitcnt vmcnt(0)" ::: "memory");

#define Q_BLOCK(NLO, MLO, BASEV) \
    __builtin_amdgcn_s_setprio(1); \
    _Pragma("unroll") \
    for (int n = (NLO); n < (NLO) + 2; ++n) \
      _Pragma("unroll") \
      for (int mt = (MLO); mt < (MLO) + 4; ++mt) \
        _Pragma("unroll") \
        for (int kk = 0; kk < 2; ++kk) \
          acc[mt][n] = __builtin_amdgcn_mfma_f32_16x16x32_bf16( \
              af[(mt + 2 - 2 * kk + (BASEV)) % 10], bfr[n][kk], acc[mt][n], 0, 0, 0); \
    __builtin_amdgcn_s_setprio(0);

#define TILE_BODY(BASEV, KT, DOSTAGE, DOFRESH) { \
    const int kt_  = (KT); \
    const int cur_ = kt_ & 1; \
    const unsigned short* Bs = &sB[cur_][0]; \
    SBAR(); \
    bf16x8 bfr[4][2]; \
    _Pragma("unroll") \
    for (int n = 0; n < 4; ++n) { \
        int rb = (wn * 64 + n * 16 + lrow) * BK; \
        bfr[n][0] = *(const bf16x8*)&Bs[rb + ca0]; \
        bfr[n][1] = *(const bf16x8*)&Bs[rb + ca1]; \
    } \
    Q_BLOCK(0, 4, BASEV) \
    Q_BLOCK(0, 0, BASEV) \
    Q_BLOCK(2, 4, BASEV) \
    asm volatile("s_waitcnt vmcnt(0)" ::: "memory"); \
    SBAR(); \
    if (DOSTAGE) stage_tile(cur_, (kt_ + 2) * BK); \
    if (DOFRESH) { \
        const unsigned short* An = &sA[cur_ ^ 1][0]; \
        const int lr0 = wm * 32 + lrow; \
        af[(0 + (BASEV) + 6) % 10] = *(const bf16x8*)&An[(lr0     ) * BK + ca1]; \
        af[(1 + (BASEV) + 6) % 10] = *(const bf16x8*)&An[(lr0 + 16) * BK + ca1]; \
        af[(2 + (BASEV) + 6) % 10] = *(const bf16x8*)&An[(lr0     ) * BK + ca0]; \
        af[(3 + (BASEV) + 6) % 10] = *(const bf16x8*)&An[(lr0 + 16) * BK + ca0]; \
    } \
    Q_BLOCK(2, 0, BASEV) \
  }

    for (int s = 0; s < 12; ++s) {
        int kt = s * 5;
        TILE_BODY(0, kt + 0, true, true)
        TILE_BODY(6, kt + 1, true, true)
        TILE_BODY(2, kt + 2, true, true)
        TILE_BODY(8, kt + 3, true, true)
        TILE_BODY(4, kt + 4, true, true)
    }
    TILE_BODY(0, 60, true,  true)
    TILE_BODY(6, 61, true,  true)
    TILE_BODY(2, 62, false, true)
    TILE_BODY(8, 63, false, false)

#undef TILE_BODY
#undef Q_BLOCK

    // ---- epilogue: C/D layout col=lane&15, row=(lane>>4)*4+r ----
    float* outb = out + ((size_t)b * NSEQ + i0 + wm * 128) * DDIM + n0 + wn * 64;
#pragma unroll
    for (int m = 0; m < 8; ++m)
#pragma unroll
        for (int n = 0; n < 4; ++n)
#pragma unroll
            for (int r = 0; r < 4; ++r)
                outb[(size_t)(m * 16 + lhi * 4 + r) * DDIM + n * 16 + lrow] = acc[m][n][r];
}

// ---------------------------------------------------------------------------
extern "C" void kernel_launch(void* const* d_in, const int* in_sizes, int n_in,
                              void* d_out, int out_size, void* d_ws, size_t ws_size,
                              hipStream_t stream) {
    const float* x    = (const float*)d_in[0];
    const float* pos  = (const float*)d_in[1];
    const float* zero = (const float*)d_in[2];
    const float* neg  = (const float*)d_in[3];
    float* out = (float*)d_out;

    unsigned short* Tm = (unsigned short*)d_ws;                    // 32 MiB
    unsigned short* xT = Tm + (size_t)NSEQ * NSEQ;                 // 32 MiB

    build_T<<<dim3(NSEQ * NSEQ / 8 / 256), 256, 0, stream>>>(pos, zero, neg, Tm);
    transpose_x<<<dim3(NSEQ / 64, DDIM / 64, NB), 256, 0, stream>>>(x, xT);
    gemm_toep_ring<<<dim3(NSEQ / BMN * (DDIM / BMN) * NB), 512, 0, stream>>>(Tm, xT, out);
}

// Round 5
// 161.794 us; speedup vs baseline: 1.4552x; 1.0144x over previous
//
#include <hip/hip_runtime.h>
#include <hip/hip_bf16.h>
#include <stdint.h>

#define NSEQ 4096
#define DDIM 512
#define NB   8

#define BMN 256
#define BK  64
#define NT  (NSEQ / BK)   // 64 K-tiles

typedef float f32x16 __attribute__((ext_vector_type(16)));
typedef __bf16 bf16x8 __attribute__((ext_vector_type(8)));

typedef const void __attribute__((address_space(1))) gvoid_t;
typedef void __attribute__((address_space(3))) svoid_t;

#define SBAR() do { __builtin_amdgcn_s_barrier(); asm volatile("" ::: "memory"); } while (0)

__device__ __forceinline__ unsigned short f2bf(float f) {
    union { float f; unsigned int u; } v;
    v.f = f;
    unsigned int u = v.u;
    u += 0x7FFFu + ((u >> 16) & 1u);   // RNE
    return (unsigned short)(u >> 16);
}

// ---------------------------------------------------------------------------
// Kernel 1: T[i][j] = bf16(exp(clamp(w(i-j))))
// ---------------------------------------------------------------------------
__global__ void build_T(const float* __restrict__ pos,
                        const float* __restrict__ zero,
                        const float* __restrict__ neg,
                        unsigned short* __restrict__ T) {
    int tid = blockIdx.x * blockDim.x + threadIdx.x;
    int i  = tid >> 9;
    int j0 = (tid & 511) << 3;
    float z = zero[0];
    unsigned short r[8];
#pragma unroll
    for (int e = 0; e < 8; ++e) {
        int j = j0 + e;
        int d = i - j;
        float v;
        if (d > 0)       v = pos[d - 1];
        else if (d == 0) v = z;
        else             v = neg[NSEQ - 1 + d];
        v = fminf(fmaxf(v, -60.0f), 30.0f);
        r[e] = f2bf(__expf(v));
    }
    uint4 o;
    o.x = (unsigned int)r[0] | ((unsigned int)r[1] << 16);
    o.y = (unsigned int)r[2] | ((unsigned int)r[3] << 16);
    o.z = (unsigned int)r[4] | ((unsigned int)r[5] << 16);
    o.w = (unsigned int)r[6] | ((unsigned int)r[7] << 16);
    *(uint4*)(T + (size_t)i * NSEQ + j0) = o;
}

// ---------------------------------------------------------------------------
// Kernel 2: xT[b][d][j] = bf16(x[b][j][d])
// ---------------------------------------------------------------------------
__global__ void transpose_x(const float* __restrict__ x,
                            unsigned short* __restrict__ xT) {
    __shared__ unsigned short tile[64][66];
    int b  = blockIdx.z;
    int j0 = blockIdx.x * 64;
    int d0 = blockIdx.y * 64;
    const float* xb = x + (size_t)b * NSEQ * DDIM;
#pragma unroll
    for (int e = 0; e < 16; ++e) {
        int idx = e * 256 + threadIdx.x;
        int r = idx >> 6, c = idx & 63;
        tile[r][c] = f2bf(xb[(size_t)(j0 + r) * DDIM + d0 + c]);
    }
    __syncthreads();
    unsigned short* xtb = xT + (size_t)b * DDIM * NSEQ;
#pragma unroll
    for (int e = 0; e < 16; ++e) {
        int idx = e * 256 + threadIdx.x;
        int r = idx >> 6, c = idx & 63;
        xtb[(size_t)(d0 + r) * NSEQ + j0 + c] = tile[c][r];
    }
}

// ---------------------------------------------------------------------------
// Kernel 3: out[b] = T @ x[b], 32x32x16 MFMA + Toeplitz A-register-ring.
// 256x256x64 tiles, 8 waves (2M x 4N), wave tile 128x64 (mt 0..3 x n 0..1).
// A-frag key/16 = 2mt-kk-4kt -> 12-slot ring, slot=(key16+3) mod 12
// (absolutely invariant). 4 fresh frags/tile from sA[(kt+1)%3].
// 3 LDS buffers -> ONE barrier + ONE counted vmcnt(5) per K-tile.
// ---------------------------------------------------------------------------
__global__ __launch_bounds__(512, 2) void gemm_toep32(
        const unsigned short* __restrict__ T,    // [NSEQ][NSEQ] bf16
        const unsigned short* __restrict__ xT,   // [NB][DDIM][NSEQ] bf16
        float* __restrict__ out) {               // [NB][NSEQ][DDIM] f32
    __shared__ __attribute__((aligned(16))) unsigned short sA[3][64 * BK];   // 8 KB x3
    __shared__ __attribute__((aligned(16))) unsigned short sB[3][BMN * BK];  // 32 KB x3

    const int tid  = threadIdx.x;
    const int lane = tid & 63;
    const int wid  = tid >> 6;      // 0..7
    const int wm   = wid >> 2;      // 0..1 -> 128-row half
    const int wn   = wid & 3;       // 0..3 -> 64-col quarter
    const int l31  = lane & 31;
    const int lhi2 = lane >> 5;     // 0..1

    // ---- XCD-aware bijective block swizzle (256 blocks, 8 XCDs) ----
    int lin = blockIdx.x;
    int swz = (lin & 7) * 32 + (lin >> 3);
    int it  = swz >> 4;
    int tn  = (swz & 15) & 1;
    int b   = (swz & 15) >> 1;
    const int i0 = it * BMN;
    const int n0 = tn * BMN;

    const unsigned short* Ag = T + (size_t)i0 * NSEQ;
    const unsigned short* Bg = xT + ((size_t)b * DDIM + n0) * NSEQ;

    // staging geometry: 8 rows x 128B per instr, pre-swizzled source chunk
    const int srow = lane >> 3;
    const int schk = (lane & 7) ^ srow;
    const int agrow = (wid < 4) ? (wid * 8 + srow) : (128 + (wid - 4) * 8 + srow);
    const uint32_t offA = (uint32_t)agrow * NSEQ + schk * 8;
    uint32_t offB[4];
#pragma unroll
    for (int q = 0; q < 4; ++q)
        offB[q] = (uint32_t)((q * 8 + wid) * 8 + srow) * NSEQ + schk * 8;

#define STAGE(BUF, K0) do { \
    __builtin_amdgcn_global_load_lds( \
        (gvoid_t*)(const void*)(Ag + offA + (K0)), \
        (svoid_t*)(void*)(&sA[BUF][0] + wid * 512), 16, 0, 0); \
    _Pragma("unroll") \
    for (int q_ = 0; q_ < 4; ++q_) \
        __builtin_amdgcn_global_load_lds( \
            (gvoid_t*)(const void*)(Bg + offB[q_] + (K0)), \
            (svoid_t*)(void*)(&sB[BUF][0] + (q_ * 8 + wid) * 512), 16, 0, 0); \
} while (0)

    f32x16 acc[4][2];
#pragma unroll
    for (int m = 0; m < 4; ++m)
#pragma unroll
        for (int n = 0; n < 2; ++n)
#pragma unroll
            for (int r = 0; r < 16; ++r)
                acc[m][n][r] = 0.f;

    // ---- A-frag ring init for tile 0 (slots 0..9 = key16 -3..6) ----
    bf16x8 af[12];
#pragma unroll
    for (int kb = -3; kb <= 6; ++kb) {
        int mt = (kb <= 0) ? 0 : ((kb + 1) >> 1);
        int kk = 2 * mt - kb;
        af[kb + 3] = *(const bf16x8*)(T +
            (size_t)(i0 + wm * 128 + mt * 32 + l31) * NSEQ + kk * 16 + lhi2 * 8);
    }

    STAGE(0, 0);
    STAGE(1, BK);
    asm volatile("s_waitcnt vmcnt(5)" ::: "memory");
    SBAR();

// slot of frag (mt,kk) in tile with kt%3==KTM  (compile-time under unroll)
#define SLOT(MT, KK, KTM) (((2 * (MT) - (KK) - 4 * (KTM) + 3) % 12 + 12) % 12)
// slot of fresh frag j (= (mt0, kk=3-j) of tile kt+1), written in body kt
#define FSLOT(J, KTM) ((((J) - 4 * (((KTM) + 1) % 3)) % 12 + 12) % 12)

#define QC(MT, KTM) \
    _Pragma("unroll") \
    for (int n_ = 0; n_ < 2; ++n_) \
      _Pragma("unroll") \
      for (int kk_ = 0; kk_ < 4; ++kk_) \
        acc[MT][n_] = __builtin_amdgcn_mfma_f32_32x32x16_bf16( \
            af[SLOT(MT, kk_, KTM)], bfr[n_][kk_], acc[MT][n_], 0, 0, 0);

#define TILE_BODY(KTM, KT, DOSTAGE, DOFRESH) { \
    const unsigned short* Bs = &sB[KTM][0]; \
    bf16x8 bfr[2][4]; \
    _Pragma("unroll") \
    for (int n_ = 0; n_ < 2; ++n_) { \
        int row_ = wn * 64 + n_ * 32 + l31; \
        int rb_ = row_ * BK, rx_ = row_ & 7; \
        _Pragma("unroll") \
        for (int kk_ = 0; kk_ < 4; ++kk_) \
            bfr[n_][kk_] = *(const bf16x8*)&Bs[rb_ + (((kk_ * 2 + lhi2) ^ rx_) << 3)]; \
    } \
    __builtin_amdgcn_s_setprio(1); \
    QC(3, KTM) \
    QC(2, KTM) \
    __builtin_amdgcn_s_setprio(0); \
    if (DOSTAGE) { \
        STAGE((((KTM) + 2) % 3), (KT + 2) * BK); \
        asm volatile("s_waitcnt vmcnt(5)" ::: "memory"); \
    } else { \
        asm volatile("s_waitcnt vmcnt(0)" ::: "memory"); \
    } \
    SBAR(); \
    if (DOFRESH) { \
        const unsigned short* An = &sA[((KTM) + 1) % 3][0]; \
        int row_ = wm * 32 + l31; \
        int rb_ = row_ * 64, rx_ = row_ & 7; \
        af[FSLOT(0, KTM)] = *(const bf16x8*)&An[rb_ + (((3 * 2 + lhi2) ^ rx_) << 3)]; \
        af[FSLOT(1, KTM)] = *(const bf16x8*)&An[rb_ + (((2 * 2 + lhi2) ^ rx_) << 3)]; \
        af[FSLOT(2, KTM)] = *(const bf16x8*)&An[rb_ + (((1 * 2 + lhi2) ^ rx_) << 3)]; \
        af[FSLOT(3, KTM)] = *(const bf16x8*)&An[rb_ + (((0 * 2 + lhi2) ^ rx_) << 3)]; \
    } \
    __builtin_amdgcn_s_setprio(1); \
    QC(1, KTM) \
    QC(0, KTM) \
    __builtin_amdgcn_s_setprio(0); \
}

    for (int s = 0; s < 20; ++s) {
        const int kt = s * 3;
        TILE_BODY(0, kt, 1, 1)
        TILE_BODY(1, (kt + 1), 1, 1)
        TILE_BODY(2, (kt + 2), 1, 1)
    }
    TILE_BODY(0, 60, 1, 1)
    TILE_BODY(1, 61, 1, 1)
    TILE_BODY(2, 62, 0, 1)
    TILE_BODY(0, 63, 0, 0)

#undef TILE_BODY
#undef QC
#undef SLOT
#undef FSLOT
#undef STAGE

    // ---- epilogue: 32x32 C/D layout col=lane&31, row=(reg&3)+8*(reg>>2)+4*(lane>>5)
    float* outb = out + ((size_t)b * NSEQ + i0 + wm * 128) * DDIM + n0 + wn * 64;
#pragma unroll
    for (int mt = 0; mt < 4; ++mt)
#pragma unroll
        for (int n = 0; n < 2; ++n)
#pragma unroll
            for (int r = 0; r < 16; ++r) {
                int row = mt * 32 + (r & 3) + 8 * (r >> 2) + 4 * lhi2;
                outb[(size_t)row * DDIM + n * 32 + l31] = acc[mt][n][r];
            }
}

// ---------------------------------------------------------------------------
extern "C" void kernel_launch(void* const* d_in, const int* in_sizes, int n_in,
                              void* d_out, int out_size, void* d_ws, size_t ws_size,
                              hipStream_t stream) {
    const float* x    = (const float*)d_in[0];
    const float* pos  = (const float*)d_in[1];
    const float* zero = (const float*)d_in[2];
    const float* neg  = (const float*)d_in[3];
    float* out = (float*)d_out;

    unsigned short* Tm = (unsigned short*)d_ws;                    // 32 MiB
    unsigned short* xT = Tm + (size_t)NSEQ * NSEQ;                 // 32 MiB

    build_T<<<dim3(NSEQ * NSEQ / 8 / 256), 256, 0, stream>>>(pos, zero, neg, Tm);
    transpose_x<<<dim3(NSEQ / 64, DDIM / 64, NB), 256, 0, stream>>>(x, xT);
    gemm_toep32<<<dim3(NSEQ / BMN * (DDIM / BMN) * NB), 512, 0, stream>>>(Tm, xT, out);
}